// Round 6
// baseline (338.540 us; speedup 1.0000x reference)
//
#include <hip/hip_runtime.h>

// Attention_29231547416680: B=4, N=2048, CH=512, H=8, D=64, fp32 in/out.
// R6 = R5 with V fragments loaded directly from global (L2) instead of LDS:
//      LDS pipe ops/wave-iter 44 -> 26 (the measured bottleneck), V traffic
//      moved to the idle VMEM pipe. K staging/QK^T/softmax/P-bounce unchanged.

typedef float f32x4 __attribute__((ext_vector_type(4)));
typedef short short8 __attribute__((ext_vector_type(8)));

#define MFMA(a, b, c) __builtin_amdgcn_mfma_f32_16x16x32_bf16((a), (b), (c), 0, 0, 0)

#if __has_builtin(__builtin_amdgcn_exp2f)
#define EXP2(x) __builtin_amdgcn_exp2f(x)
#else
#define EXP2(x) exp2f(x)
#endif

#define NBH 32
#define NSEQ 2048
#define DH 64

__device__ __forceinline__ unsigned short f2bf(float f) {
  unsigned int u = __float_as_uint(f);
  u += 0x7fffu + ((u >> 16) & 1u);  // RTNE
  return (unsigned short)(u >> 16);
}
__device__ __forceinline__ float bf2f(unsigned short h) {
  return __uint_as_float(((unsigned int)h) << 16);
}
__device__ __forceinline__ void split_bf16(float f, unsigned short& hi, unsigned short& lo) {
  hi = f2bf(f);
  lo = f2bf(f - bf2f(hi));
}

// packed dword: bf16(hi) in low16, bf16(lo, truncated split) in high16
__device__ __forceinline__ unsigned pack_hilo(float p) {
  unsigned u = __float_as_uint(p);
  float lo = p - __uint_as_float(u & 0xffff0000u);
  unsigned ul = __float_as_uint(lo);
#if __has_builtin(__builtin_amdgcn_perm)
  return __builtin_amdgcn_perm(ul, u, 0x07060302u);
#else
  return (u >> 16) | (ul & 0xffff0000u);
#endif
}
__device__ __forceinline__ unsigned lo16pair(unsigned d0, unsigned d1) {
#if __has_builtin(__builtin_amdgcn_perm)
  return __builtin_amdgcn_perm(d1, d0, 0x05040100u);
#else
  return (d0 & 0xffffu) | (d1 << 16);
#endif
}
__device__ __forceinline__ unsigned hi16pair(unsigned d0, unsigned d1) {
#if __has_builtin(__builtin_amdgcn_perm)
  return __builtin_amdgcn_perm(d1, d0, 0x07060302u);
#else
  return (d0 >> 16) | (d1 & 0xffff0000u);
#endif
}

// ---------------- mask bit-pack: 1024 blocks, thread owns 64 elems ----------------
__global__ __launch_bounds__(256) void pack_mask(const void* __restrict__ mraw,
                                                 unsigned long long* __restrict__ Mp) {
  const int tid = threadIdx.x;
  __shared__ int s_bad;
  if (tid == 0) s_bad = 0;
  __syncthreads();
  const unsigned int* mw32 = (const unsigned int*)mraw;
  {
    // probe the first 2 KB only (in-bounds for both 1B and 4B encodings)
    unsigned int w0 = mw32[tid], w1 = mw32[256 + tid];
    bool ok = (w0 == 0u || w0 == 1u || w0 == 0x3f800000u) &&
              (w1 == 0u || w1 == 1u || w1 == 0x3f800000u);
    if (!ok) s_bad = 1;
  }
  __syncthreads();
  const size_t e0 = (size_t)blockIdx.x * 16384 + (size_t)tid * 64;
  unsigned long long bits = 0ull;
  if (s_bad == 0) {
    const uint4* p = (const uint4*)mw32 + (e0 >> 2);
#pragma unroll
    for (int j = 0; j < 16; ++j) {
      uint4 v = p[j];
      unsigned nib = (v.x != 0u) | ((v.y != 0u) << 1) | ((v.z != 0u) << 2) | ((v.w != 0u) << 3);
      bits |= (unsigned long long)nib << (j * 4);
    }
  } else {
    const uint4* p = (const uint4*)((const unsigned char*)mraw + e0);
#pragma unroll
    for (int j = 0; j < 4; ++j) {
      uint4 v = p[j];
      unsigned dw[4] = {v.x, v.y, v.z, v.w};
#pragma unroll
      for (int d = 0; d < 4; ++d) {
        unsigned nib = (((dw[d]) & 0xffu) != 0u) | ((((dw[d] >> 8) & 0xffu) != 0u) << 1) |
                       ((((dw[d] >> 16) & 0xffu) != 0u) << 2) | ((((dw[d] >> 24) & 0xffu) != 0u) << 3);
        bits |= (unsigned long long)nib << ((j * 4 + d) * 4);
      }
    }
  }
  Mp[e0 >> 6] = bits;
}

// ---------------- Kernel 1: QKV projection (z-merged) ----------------
// Q pre-scaled by log2(e)/sqrt(128); Q,K: [bh][n][64] hi/lo; V: [bh][64][n] hi/lo.
__global__ __launch_bounds__(256) void proj_kernel(
    const float* __restrict__ x,
    const float* __restrict__ Wq, const float* __restrict__ Wk, const float* __restrict__ Wv,
    unsigned short* __restrict__ Qh, unsigned short* __restrict__ Ql,
    unsigned short* __restrict__ Kh, unsigned short* __restrict__ Kl,
    unsigned short* __restrict__ Vh, unsigned short* __restrict__ Vl) {
  const int tid = threadIdx.x;
  const int w = tid >> 6, l = tid & 63;
  const int m0 = blockIdx.x * 64;
  const int h = blockIdx.y;
  const int lrow = l & 15, lg = l >> 4;
  const int rw = (w >> 1) * 32, cw = (w & 1) * 32;

  union LDSU {
    struct {
      unsigned short Ah[64][48], Al[64][48];
      unsigned short Bh[3][64][48], Bl[3][64][48];
    } s;
    unsigned short ob[6][64][72];  // epilogue bounce (row stride 144B, 16B aligned)
  };
  __shared__ LDSU u;

  f32x4 acc[3][2][2] = {};
  const int srow = tid >> 2, sc8 = (tid & 3) * 8;

  for (int k0 = 0; k0 < 512; k0 += 32) {
    __syncthreads();
    {
      const float* xs = &x[(size_t)(m0 + srow) * 512 + k0 + sc8];
      float4 a0 = *(const float4*)xs, a1 = *(const float4*)(xs + 4);
      unsigned short h0, l0, h1, l1, h2, l2, h3, l3;
      split_bf16(a0.x, h0, l0); split_bf16(a0.y, h1, l1);
      split_bf16(a0.z, h2, l2); split_bf16(a0.w, h3, l3);
      *(ushort4*)&u.s.Ah[srow][sc8] = make_ushort4(h0, h1, h2, h3);
      *(ushort4*)&u.s.Al[srow][sc8] = make_ushort4(l0, l1, l2, l3);
      split_bf16(a1.x, h0, l0); split_bf16(a1.y, h1, l1);
      split_bf16(a1.z, h2, l2); split_bf16(a1.w, h3, l3);
      *(ushort4*)&u.s.Ah[srow][sc8 + 4] = make_ushort4(h0, h1, h2, h3);
      *(ushort4*)&u.s.Al[srow][sc8 + 4] = make_ushort4(l0, l1, l2, l3);
      const float* Wz[3] = {Wq, Wk, Wv};
#pragma unroll
      for (int z = 0; z < 3; ++z) {
        const float* ws = &Wz[z][(size_t)(h * 64 + srow) * 512 + k0 + sc8];
        float4 b0 = *(const float4*)ws, b1 = *(const float4*)(ws + 4);
        split_bf16(b0.x, h0, l0); split_bf16(b0.y, h1, l1);
        split_bf16(b0.z, h2, l2); split_bf16(b0.w, h3, l3);
        *(ushort4*)&u.s.Bh[z][srow][sc8] = make_ushort4(h0, h1, h2, h3);
        *(ushort4*)&u.s.Bl[z][srow][sc8] = make_ushort4(l0, l1, l2, l3);
        split_bf16(b1.x, h0, l0); split_bf16(b1.y, h1, l1);
        split_bf16(b1.z, h2, l2); split_bf16(b1.w, h3, l3);
        *(ushort4*)&u.s.Bh[z][srow][sc8 + 4] = make_ushort4(h0, h1, h2, h3);
        *(ushort4*)&u.s.Bl[z][srow][sc8 + 4] = make_ushort4(l0, l1, l2, l3);
      }
    }
    __syncthreads();

    short8 ah[2], al[2];
#pragma unroll
    for (int t = 0; t < 2; ++t) {
      ah[t] = *(const short8*)&u.s.Ah[rw + 16 * t + lrow][lg * 8];
      al[t] = *(const short8*)&u.s.Al[rw + 16 * t + lrow][lg * 8];
    }
#pragma unroll
    for (int z = 0; z < 3; ++z) {
      short8 bh[2], bl[2];
#pragma unroll
      for (int t = 0; t < 2; ++t) {
        bh[t] = *(const short8*)&u.s.Bh[z][cw + 16 * t + lrow][lg * 8];
        bl[t] = *(const short8*)&u.s.Bl[z][cw + 16 * t + lrow][lg * 8];
      }
#pragma unroll
      for (int tm = 0; tm < 2; ++tm)
#pragma unroll
        for (int tn = 0; tn < 2; ++tn) {
          acc[z][tm][tn] = MFMA(ah[tm], bh[tn], acc[z][tm][tn]);
          acc[z][tm][tn] = MFMA(ah[tm], bl[tn], acc[z][tm][tn]);
          acc[z][tm][tn] = MFMA(al[tm], bh[tn], acc[z][tm][tn]);
        }
    }
  }

  __syncthreads();  // staging LDS dead; reuse as obuf
  const float qsc = 1.4426950408889634f * 0.08838834764831845f;  // log2e/sqrt(128)
#pragma unroll
  for (int z = 0; z < 3; ++z)
#pragma unroll
    for (int tm = 0; tm < 2; ++tm)
#pragma unroll
      for (int tn = 0; tn < 2; ++tn) {
        int d = cw + tn * 16 + lrow;
        int nl = rw + tm * 16 + lg * 4;
#pragma unroll
        for (int r = 0; r < 4; ++r) {
          float v = acc[z][tm][tn][r];
          if (z == 0) v *= qsc;
          unsigned short hi, lo;
          split_bf16(v, hi, lo);
          if (z < 2) {
            u.ob[2 * z][nl + r][d] = hi;
            u.ob[2 * z + 1][nl + r][d] = lo;
          } else {
            u.ob[4][d][nl + r] = hi;
            u.ob[5][d][nl + r] = lo;
          }
        }
      }
  __syncthreads();

  const int orow = tid >> 2, oc = (tid & 3) * 16;
  const int b = m0 >> 11, n0 = m0 & 2047, bhid = b * 8 + h;
  {
    unsigned short* QK[4] = {Qh, Ql, Kh, Kl};
#pragma unroll
    for (int p = 0; p < 4; ++p) {
      size_t base = ((size_t)bhid * 2048 + n0 + orow) * 64 + oc;
      *(short8*)&QK[p][base] = *(const short8*)&u.ob[p][orow][oc];
      *(short8*)&QK[p][base + 8] = *(const short8*)&u.ob[p][orow][oc + 8];
    }
    unsigned short* VV[2] = {Vh, Vl};
#pragma unroll
    for (int p = 0; p < 2; ++p) {
      size_t vb = ((size_t)bhid * 64 + orow) * 2048 + n0 + oc;
      *(short8*)&VV[p][vb] = *(const short8*)&u.ob[4 + p][orow][oc];
      *(short8*)&VV[p][vb + 8] = *(const short8*)&u.ob[4 + p][orow][oc + 8];
    }
  }
}

// ---------------- Kernel 2: flash attention ----------------
// 512 blocks (XCD-swizzled), 512 threads = 8 waves; wave w owns q rows q0+w*16..+15.
// K hi/lo staged in LDS; V hi/lo fragments loaded directly from global (L2).
__global__ __launch_bounds__(512, 4) void attn_kernel(
    const unsigned short* __restrict__ Qh, const unsigned short* __restrict__ Ql,
    const unsigned short* __restrict__ Kh, const unsigned short* __restrict__ Kl,
    const unsigned short* __restrict__ Vh, const unsigned short* __restrict__ Vl,
    const unsigned long long* __restrict__ Mp, float* __restrict__ out) {
  const int tid = threadIdx.x;
  const int w = tid >> 6, l = tid & 63;
  // XCD swizzle: 64 consecutive remapped ids (4 whole bh) per XCD
  const int wl = blockIdx.x;
  const int rm = (wl & 7) * 64 + (wl >> 3);
  const int q0 = (rm & 15) * 128;
  const int bh = rm >> 4;
  const int b = bh >> 3, h = bh & 7;
  const int lrow = l & 15, lg = l >> 4, lsw = (l & 7) << 4;

  const unsigned short* Qhb = Qh + (size_t)bh * NSEQ * DH;
  const unsigned short* Qlb = Ql + (size_t)bh * NSEQ * DH;
  const unsigned short* Khb = Kh + (size_t)bh * NSEQ * DH;
  const unsigned short* Klb = Kl + (size_t)bh * NSEQ * DH;
  const unsigned long long* Mb = Mp + (size_t)b * NSEQ * 32;
  float* Ob = out + (size_t)b * NSEQ * 512 + h * 64;

  __shared__ __align__(16) unsigned short kvb[2][64][64];  // Kh,Kl swizzled, 16KB
  __shared__ __align__(16) unsigned int pb[8][16][64];     // packed P per wave, 32KB

  char* kv0 = (char*)&kvb[0][0][0];
  char* pbw = (char*)&pb[0][0][0] + w * 4096;

  // hoisted swizzled LDS offsets (all loop-invariant)
  const int rb0 = lrow * 128 + ((lg * 16) ^ lsw);        // dc = 0
  const int rb1 = lrow * 128 + ((64 + lg * 16) ^ lsw);   // dc = 1
  int pwoff[4];  // P write: full linear offset XOR'd (avoids XOR+add carry bug)
#pragma unroll
  for (int kt = 0; kt < 4; ++kt) pwoff[kt] = (lrow * 256 + kt * 64 + lg * 16) ^ lsw;
  const int pr0 = lrow * 256 + ((lg * 32) ^ lsw);        // P read, first 16B (+kc*128)
  const int pr1 = lrow * 256 + (((lg * 32) + 16) ^ lsw); // P read, second 16B

  // Q fragments (B-operand): row = q0+w*16+lrow, k = lg*8 (+dc*32)
  const size_t qoff = (size_t)(q0 + w * 16 + lrow) * 64 + lg * 8;
  short8 qh[2], ql[2];
#pragma unroll
  for (int dc = 0; dc < 2; ++dc) {
    qh[dc] = *(const short8*)(Qhb + qoff + dc * 32);
    ql[dc] = *(const short8*)(Qlb + qoff + dc * 32);
  }

  // V fragment base pointers (advance by 64 per k-tile)
  const unsigned short* vbh = Vh + (size_t)bh * DH * NSEQ + (size_t)lrow * 2048 + lg * 8;
  const unsigned short* vbl = Vl + (size_t)bh * DH * NSEQ + (size_t)lrow * 2048 + lg * 8;

  f32x4 o[4] = {};
  float mrun = -1e30f, lrun = 0.0f;  // per lane: softmax state of q-row (l&15)
  const int qglob = q0 + w * 16 + lrow;

  // async staging: K tile t loaded into regs during tile t-1's compute
  const int stg_row = tid >> 3, stg_c = (tid & 7) * 8;
  const int sdst = stg_row * 128 + ((stg_c * 2) ^ ((stg_row & 7) << 4));
  size_t koff = (size_t)stg_row * 64 + stg_c;
  short8 st0 = *(const short8*)(Khb + koff);
  short8 st1 = *(const short8*)(Klb + koff);

  for (int k0 = 0; k0 < 2048; k0 += 64) {
    __syncthreads();  // all waves done reading previous K tile
    *(short8*)(kv0 + sdst) = st0;
    *(short8*)(kv0 + sdst + 8192) = st1;
    __syncthreads();
    if (k0 < 2048 - 64) {  // prefetch next K tile into regs
      koff += 4096;
      st0 = *(const short8*)(Khb + koff);
      st1 = *(const short8*)(Klb + koff);
    }

    // ---- packed mask word + V batch 1 (dt 0..1): issue early, hide L2 latency ----
    const unsigned long long mw = Mb[(size_t)qglob * 32 + (k0 >> 6)];
    short8 vhf[4][2], vlf[4][2];
#pragma unroll
    for (int dt = 0; dt < 2; ++dt)
#pragma unroll
      for (int kc = 0; kc < 2; ++kc) {
        const int vo = dt * 16 * 2048 + kc * 32;
        vhf[dt][kc] = *(const short8*)(vbh + vo);
        vlf[dt][kc] = *(const short8*)(vbl + vo);
      }

    // ---- S^T = K Q^T : lane holds S[k=kt*16+lg*4+r][q=lrow] ----
    f32x4 s[4] = {};
#pragma unroll
    for (int dc = 0; dc < 2; ++dc) {
      const int rb = dc ? rb1 : rb0;
#pragma unroll
      for (int kt = 0; kt < 4; ++kt) {
        short8 kh = *(const short8*)(kv0 + rb + kt * 2048);
        short8 kl = *(const short8*)(kv0 + rb + kt * 2048 + 8192);
        s[kt] = MFMA(kh, qh[dc], s[kt]);
        s[kt] = MFMA(kh, ql[dc], s[kt]);
        s[kt] = MFMA(kl, qh[dc], s[kt]);
      }
    }

    // ---- mask + lane-local online softmax (exp2 domain) ----
#pragma unroll
    for (int kt = 0; kt < 4; ++kt) {
      unsigned nib = ((unsigned)(mw >> (kt * 16 + lg * 4))) & 0xFu;
#pragma unroll
      for (int r = 0; r < 4; ++r) s[kt][r] = ((nib >> r) & 1u) ? -1e30f : s[kt][r];
    }
    float mx = s[0][0];
#pragma unroll
    for (int kt = 0; kt < 4; ++kt)
#pragma unroll
      for (int r = 0; r < 4; ++r) mx = fmaxf(mx, s[kt][r]);
    mx = fmaxf(mx, __shfl_xor(mx, 16));
    mx = fmaxf(mx, __shfl_xor(mx, 32));
    const bool grow = __any(mx > mrun + 11.0f);  // defer-max: p bounded by 2^11
    const float mnew = grow ? fmaxf(mrun, mx) : mrun;

    float rs = 0.0f;
#pragma unroll
    for (int kt = 0; kt < 4; ++kt) {
      float p0 = EXP2(s[kt][0] - mnew);
      float p1 = EXP2(s[kt][1] - mnew);
      float p2 = EXP2(s[kt][2] - mnew);
      float p3 = EXP2(s[kt][3] - mnew);
      rs += (p0 + p1) + (p2 + p3);
      uint4 pk = make_uint4(pack_hilo(p0), pack_hilo(p1), pack_hilo(p2), pack_hilo(p3));
      *(uint4*)(pbw + pwoff[kt]) = pk;
    }
    rs += __shfl_xor(rs, 16);
    rs += __shfl_xor(rs, 32);
    if (grow) {
      float sc = EXP2(mrun - mnew);
      lrun = lrun * sc + rs;
      mrun = mnew;
#pragma unroll
      for (int r = 0; r < 4; ++r) {
        float so = __shfl(sc, lg * 4 + r);
#pragma unroll
        for (int dt = 0; dt < 4; ++dt) o[dt][r] *= so;
      }
    } else {
      lrun += rs;
    }

    // ---- V batch 2 (dt 2..3): s[] is dead now, regs free; hidden by P-read+PV ----
#pragma unroll
    for (int dt = 2; dt < 4; ++dt)
#pragma unroll
      for (int kc = 0; kc < 2; ++kc) {
        const int vo = dt * 16 * 2048 + kc * 32;
        vhf[dt][kc] = *(const short8*)(vbh + vo);
        vlf[dt][kc] = *(const short8*)(vbl + vo);
      }
    vbh += 64;
    vbl += 64;

    // ---- O += P V  (P from packed dwords; same-wave LDS write->read) ----
    short8 pah[2], pal[2];
#pragma unroll
    for (int kc = 0; kc < 2; ++kc) {
      uint4 d0 = *(const uint4*)(pbw + pr0 + kc * 128);
      uint4 d1 = *(const uint4*)(pbw + pr1 + kc * 128);
      union PS { uint4 q; short8 s; } H, L;
      H.q.x = lo16pair(d0.x, d0.y); H.q.y = lo16pair(d0.z, d0.w);
      H.q.z = lo16pair(d1.x, d1.y); H.q.w = lo16pair(d1.z, d1.w);
      L.q.x = hi16pair(d0.x, d0.y); L.q.y = hi16pair(d0.z, d0.w);
      L.q.z = hi16pair(d1.x, d1.y); L.q.w = hi16pair(d1.z, d1.w);
      pah[kc] = H.s;
      pal[kc] = L.s;
    }
#pragma unroll
    for (int dt = 0; dt < 4; ++dt) {
#pragma unroll
      for (int kc = 0; kc < 2; ++kc) {
        o[dt] = MFMA(pah[kc], vhf[dt][kc], o[dt]);
        o[dt] = MFMA(pah[kc], vlf[dt][kc], o[dt]);
        o[dt] = MFMA(pal[kc], vhf[dt][kc], o[dt]);
      }
    }
  }

  // ---- epilogue: redistribute 1/l and store ----
#pragma unroll
  for (int r = 0; r < 4; ++r) {
    float lr = __shfl(lrun, lg * 4 + r);
    float invl = lr > 0.0f ? 1.0f / lr : 0.0f;
    int qrow = q0 + w * 16 + lg * 4 + r;
#pragma unroll
    for (int dt = 0; dt < 4; ++dt) {
      Ob[(size_t)qrow * 512 + dt * 16 + lrow] = o[dt][r] * invl;
    }
  }
}

extern "C" void kernel_launch(void* const* d_in, const int* in_sizes, int n_in,
                              void* d_out, int out_size, void* d_ws, size_t ws_size,
                              hipStream_t stream) {
  const float* x = (const float*)d_in[0];
  const void* mask = d_in[1];
  const float* Wq = (const float*)d_in[2];
  const float* Wk = (const float*)d_in[3];
  const float* Wv = (const float*)d_in[4];
  float* out = (float*)d_out;

  const size_t PLANE = (size_t)NBH * NSEQ * DH;  // 4,194,304 ushorts
  unsigned short* Qh = (unsigned short*)d_ws;
  unsigned short* Ql = Qh + PLANE;
  unsigned short* Kh = Ql + PLANE;
  unsigned short* Kl = Kh + PLANE;
  unsigned short* Vh = Kl + PLANE;
  unsigned short* Vl = Vh + PLANE;
  unsigned long long* Mp = (unsigned long long*)(Vl + PLANE);  // 2 MB

  pack_mask<<<1024, 256, 0, stream>>>(mask, Mp);
  proj_kernel<<<dim3(128, 8), 256, 0, stream>>>(x, Wq, Wk, Wv, Qh, Ql, Kh, Kl, Vh, Vl);
  attn_kernel<<<512, 512, 0, stream>>>(Qh, Ql, Kh, Kl, Vh, Vl, Mp, out);
}

// Round 8
// 213.004 us; speedup vs baseline: 1.5894x; 1.5894x over previous
//
#include <hip/hip_runtime.h>

// Attention_29231547416680: B=4, N=2048, CH=512, H=8, D=64, fp32 in/out.
// R8 = R7 with the permlane32_swap direction bug fixed via a one-time runtime
//      probe + template<bool S2> body (robust to either swap semantics).
//      32x32x16 MFMAs, 32 q-rows/wave, in-register P->B-frag conversion.

typedef float f32x4 __attribute__((ext_vector_type(4)));
typedef float f32x16 __attribute__((ext_vector_type(16)));
typedef short short8 __attribute__((ext_vector_type(8)));

#define MFMA16(a, b, c) __builtin_amdgcn_mfma_f32_16x16x32_bf16((a), (b), (c), 0, 0, 0)
#define MFMA32(a, b, c) __builtin_amdgcn_mfma_f32_32x32x16_bf16((a), (b), (c), 0, 0, 0)

#if __has_builtin(__builtin_amdgcn_exp2f)
#define EXP2(x) __builtin_amdgcn_exp2f(x)
#else
#define EXP2(x) exp2f(x)
#endif

#define NBH 32
#define NSEQ 2048
#define DH 64

__device__ __forceinline__ unsigned short f2bf(float f) {
  unsigned int u = __float_as_uint(f);
  u += 0x7fffu + ((u >> 16) & 1u);  // RTNE
  return (unsigned short)(u >> 16);
}
__device__ __forceinline__ float bf2f(unsigned short h) {
  return __uint_as_float(((unsigned int)h) << 16);
}
__device__ __forceinline__ void split_bf16(float f, unsigned short& hi, unsigned short& lo) {
  hi = f2bf(f);
  lo = f2bf(f - bf2f(hi));
}

// pack two f32 -> dword of 2 bf16 (lo16 = bf16(a), hi16 = bf16(b))
__device__ __forceinline__ unsigned cvtpk_bf16(float a, float b) {
  unsigned d;
  asm("v_cvt_pk_bf16_f32 %0, %1, %2" : "=v"(d) : "v"(a), "v"(b));
  return d;
}
__device__ __forceinline__ void permswap(unsigned& a, unsigned& b) {
  asm("v_permlane32_swap_b32 %0, %1" : "+v"(a), "+v"(b));
}

// Build the two cross-half dwords from an (even-m, odd-m) cvtpk pair.
// Result: lo = (ce.row0 | co.row0)  [lane<32 gets ce from lower half,
//         lane>=32 gets co computed by lower half];
//         hi = (ce.row1 | co.row1).
// Direction-agnostic: S2 = "a.row1 <-> b.row0" (ROCm doc), !S2 = mirror.
template <bool S2>
__device__ __forceinline__ void xsw(unsigned ce, unsigned co, unsigned& lo, unsigned& hi) {
  if (S2) { permswap(ce, co); }   // ce' = (ce.r0, co.r0), co' = (ce.r1, co.r1)
  else    { permswap(co, ce); }   // S1: co' = (ce.r1, co.r1), ce' = (ce.r0, co.r0)
  lo = ce;
  hi = co;
}

// ---------------- mask bit-pack (R5 verbatim) ----------------
__global__ __launch_bounds__(256) void pack_mask(const void* __restrict__ mraw,
                                                 unsigned long long* __restrict__ Mp) {
  const int tid = threadIdx.x;
  __shared__ int s_bad;
  if (tid == 0) s_bad = 0;
  __syncthreads();
  const unsigned int* mw32 = (const unsigned int*)mraw;
  {
    unsigned int w0 = mw32[tid], w1 = mw32[256 + tid];
    bool ok = (w0 == 0u || w0 == 1u || w0 == 0x3f800000u) &&
              (w1 == 0u || w1 == 1u || w1 == 0x3f800000u);
    if (!ok) s_bad = 1;
  }
  __syncthreads();
  const size_t e0 = (size_t)blockIdx.x * 16384 + (size_t)tid * 64;
  unsigned long long bits = 0ull;
  if (s_bad == 0) {
    const uint4* p = (const uint4*)mw32 + (e0 >> 2);
#pragma unroll
    for (int j = 0; j < 16; ++j) {
      uint4 v = p[j];
      unsigned nib = (v.x != 0u) | ((v.y != 0u) << 1) | ((v.z != 0u) << 2) | ((v.w != 0u) << 3);
      bits |= (unsigned long long)nib << (j * 4);
    }
  } else {
    const uint4* p = (const uint4*)((const unsigned char*)mraw + e0);
#pragma unroll
    for (int j = 0; j < 4; ++j) {
      uint4 v = p[j];
      unsigned dw[4] = {v.x, v.y, v.z, v.w};
#pragma unroll
      for (int d = 0; d < 4; ++d) {
        unsigned nib = (((dw[d]) & 0xffu) != 0u) | ((((dw[d] >> 8) & 0xffu) != 0u) << 1) |
                       ((((dw[d] >> 16) & 0xffu) != 0u) << 2) | ((((dw[d] >> 24) & 0xffu) != 0u) << 3);
        bits |= (unsigned long long)nib << ((j * 4 + d) * 4);
      }
    }
  }
  Mp[e0 >> 6] = bits;
}

// ---------------- Kernel 1: QKV projection (R5 verbatim) ----------------
__global__ __launch_bounds__(256) void proj_kernel(
    const float* __restrict__ x,
    const float* __restrict__ Wq, const float* __restrict__ Wk, const float* __restrict__ Wv,
    unsigned short* __restrict__ Qh, unsigned short* __restrict__ Ql,
    unsigned short* __restrict__ Kh, unsigned short* __restrict__ Kl,
    unsigned short* __restrict__ Vh, unsigned short* __restrict__ Vl) {
  const int tid = threadIdx.x;
  const int w = tid >> 6, l = tid & 63;
  const int m0 = blockIdx.x * 64;
  const int h = blockIdx.y;
  const int lrow = l & 15, lg = l >> 4;
  const int rw = (w >> 1) * 32, cw = (w & 1) * 32;

  union LDSU {
    struct {
      unsigned short Ah[64][48], Al[64][48];
      unsigned short Bh[3][64][48], Bl[3][64][48];
    } s;
    unsigned short ob[6][64][72];
  };
  __shared__ LDSU u;

  f32x4 acc[3][2][2] = {};
  const int srow = tid >> 2, sc8 = (tid & 3) * 8;

  for (int k0 = 0; k0 < 512; k0 += 32) {
    __syncthreads();
    {
      const float* xs = &x[(size_t)(m0 + srow) * 512 + k0 + sc8];
      float4 a0 = *(const float4*)xs, a1 = *(const float4*)(xs + 4);
      unsigned short h0, l0, h1, l1, h2, l2, h3, l3;
      split_bf16(a0.x, h0, l0); split_bf16(a0.y, h1, l1);
      split_bf16(a0.z, h2, l2); split_bf16(a0.w, h3, l3);
      *(ushort4*)&u.s.Ah[srow][sc8] = make_ushort4(h0, h1, h2, h3);
      *(ushort4*)&u.s.Al[srow][sc8] = make_ushort4(l0, l1, l2, l3);
      split_bf16(a1.x, h0, l0); split_bf16(a1.y, h1, l1);
      split_bf16(a1.z, h2, l2); split_bf16(a1.w, h3, l3);
      *(ushort4*)&u.s.Ah[srow][sc8 + 4] = make_ushort4(h0, h1, h2, h3);
      *(ushort4*)&u.s.Al[srow][sc8 + 4] = make_ushort4(l0, l1, l2, l3);
      const float* Wz[3] = {Wq, Wk, Wv};
#pragma unroll
      for (int z = 0; z < 3; ++z) {
        const float* ws = &Wz[z][(size_t)(h * 64 + srow) * 512 + k0 + sc8];
        float4 b0 = *(const float4*)ws, b1 = *(const float4*)(ws + 4);
        split_bf16(b0.x, h0, l0); split_bf16(b0.y, h1, l1);
        split_bf16(b0.z, h2, l2); split_bf16(b0.w, h3, l3);
        *(ushort4*)&u.s.Bh[z][srow][sc8] = make_ushort4(h0, h1, h2, h3);
        *(ushort4*)&u.s.Bl[z][srow][sc8] = make_ushort4(l0, l1, l2, l3);
        split_bf16(b1.x, h0, l0); split_bf16(b1.y, h1, l1);
        split_bf16(b1.z, h2, l2); split_bf16(b1.w, h3, l3);
        *(ushort4*)&u.s.Bh[z][srow][sc8 + 4] = make_ushort4(h0, h1, h2, h3);
        *(ushort4*)&u.s.Bl[z][srow][sc8 + 4] = make_ushort4(l0, l1, l2, l3);
      }
    }
    __syncthreads();

    short8 ah[2], al[2];
#pragma unroll
    for (int t = 0; t < 2; ++t) {
      ah[t] = *(const short8*)&u.s.Ah[rw + 16 * t + lrow][lg * 8];
      al[t] = *(const short8*)&u.s.Al[rw + 16 * t + lrow][lg * 8];
    }
#pragma unroll
    for (int z = 0; z < 3; ++z) {
      short8 bh[2], bl[2];
#pragma unroll
      for (int t = 0; t < 2; ++t) {
        bh[t] = *(const short8*)&u.s.Bh[z][cw + 16 * t + lrow][lg * 8];
        bl[t] = *(const short8*)&u.s.Bl[z][cw + 16 * t + lrow][lg * 8];
      }
#pragma unroll
      for (int tm = 0; tm < 2; ++tm)
#pragma unroll
        for (int tn = 0; tn < 2; ++tn) {
          acc[z][tm][tn] = MFMA16(ah[tm], bh[tn], acc[z][tm][tn]);
          acc[z][tm][tn] = MFMA16(ah[tm], bl[tn], acc[z][tm][tn]);
          acc[z][tm][tn] = MFMA16(al[tm], bh[tn], acc[z][tm][tn]);
        }
    }
  }

  __syncthreads();
  const float qsc = 1.4426950408889634f * 0.08838834764831845f;  // log2e/sqrt(128)
#pragma unroll
  for (int z = 0; z < 3; ++z)
#pragma unroll
    for (int tm = 0; tm < 2; ++tm)
#pragma unroll
      for (int tn = 0; tn < 2; ++tn) {
        int d = cw + tn * 16 + lrow;
        int nl = rw + tm * 16 + lg * 4;
#pragma unroll
        for (int r = 0; r < 4; ++r) {
          float v = acc[z][tm][tn][r];
          if (z == 0) v *= qsc;
          unsigned short hi, lo;
          split_bf16(v, hi, lo);
          if (z < 2) {
            u.ob[2 * z][nl + r][d] = hi;
            u.ob[2 * z + 1][nl + r][d] = lo;
          } else {
            u.ob[4][d][nl + r] = hi;
            u.ob[5][d][nl + r] = lo;
          }
        }
      }
  __syncthreads();

  const int orow = tid >> 2, oc = (tid & 3) * 16;
  const int b = m0 >> 11, n0 = m0 & 2047, bhid = b * 8 + h;
  {
    unsigned short* QK[4] = {Qh, Ql, Kh, Kl};
#pragma unroll
    for (int p = 0; p < 4; ++p) {
      size_t base = ((size_t)bhid * 2048 + n0 + orow) * 64 + oc;
      *(short8*)&QK[p][base] = *(const short8*)&u.ob[p][orow][oc];
      *(short8*)&QK[p][base + 8] = *(const short8*)&u.ob[p][orow][oc + 8];
    }
    unsigned short* VV[2] = {Vh, Vl};
#pragma unroll
    for (int p = 0; p < 2; ++p) {
      size_t vb = ((size_t)bhid * 64 + orow) * 2048 + n0 + oc;
      *(short8*)&VV[p][vb] = *(const short8*)&u.ob[4 + p][orow][oc];
      *(short8*)&VV[p][vb + 8] = *(const short8*)&u.ob[4 + p][orow][oc + 8];
    }
  }
}

// ---------------- attention body (template on permswap direction) ----------------
template <bool S2>
__device__ __forceinline__ void attn_body(
    unsigned short (&kvb)[4][64][64],
    const unsigned short* __restrict__ Qh, const unsigned short* __restrict__ Ql,
    const unsigned short* __restrict__ Kh, const unsigned short* __restrict__ Kl,
    const unsigned short* __restrict__ Vh, const unsigned short* __restrict__ Vl,
    const unsigned long long* __restrict__ Mp, float* __restrict__ out) {
  const int tid = threadIdx.x;
  const int w = tid >> 6, l = tid & 63;
  const int wl = blockIdx.x;
  const int rm = (wl & 7) * 64 + (wl >> 3);  // XCD swizzle (512 = 8*64, bijective)
  const int q0 = (rm & 15) * 128;
  const int bh = rm >> 4;
  const int b = bh >> 3, h = bh & 7;
  const int l31 = l & 31, hi = l >> 5;
  const int swz = (l31 & 7) << 4;

  const unsigned short* Qhb = Qh + (size_t)bh * NSEQ * DH;
  const unsigned short* Qlb = Ql + (size_t)bh * NSEQ * DH;
  const unsigned short* Khb = Kh + (size_t)bh * NSEQ * DH;
  const unsigned short* Klb = Kl + (size_t)bh * NSEQ * DH;
  const unsigned short* Vhb = Vh + (size_t)bh * DH * NSEQ;
  const unsigned short* Vlb = Vl + (size_t)bh * DH * NSEQ;
  const unsigned long long* Mb = Mp + (size_t)b * NSEQ * 32;
  float* Ob = out + (size_t)b * NSEQ * 512 + h * 64;

  char* kv0 = (char*)&kvb[0][0][0];

  // A-frag read addresses: row = tile32*32 + l31, colbyte = step*32 + hi*16.
  int va[4];
#pragma unroll
  for (int d = 0; d < 4; ++d) va[d] = l31 * 128 + (((d * 32) | (hi * 16)) ^ swz);

  // Q B-frags (persistent): Q[q0+w*32+l31][dstep*16 + hi*8 + 0..7]
  const size_t qoff = (size_t)(q0 + w * 32 + l31) * 64 + hi * 8;
  short8 qh[4], ql[4];
#pragma unroll
  for (int d = 0; d < 4; ++d) {
    qh[d] = *(const short8*)(Qhb + qoff + d * 16);
    ql[d] = *(const short8*)(Qlb + qoff + d * 16);
  }

  f32x16 o[2] = {};
  float mrun = -1e30f, lrun = 0.0f;
  const int qglob = q0 + w * 32 + l31;

  // staging: 256 threads x 2 chunks x 4 planes
  const int r0 = tid >> 3, ch0 = (tid & 7) * 8;
  const int r1 = (tid + 256) >> 3, ch1 = ((tid + 256) & 7) * 8;
  const int dst0 = r0 * 128 + ((ch0 * 2) ^ ((r0 & 7) << 4));
  const int dst1 = r1 * 128 + ((ch1 * 2) ^ ((r1 & 7) << 4));
  size_t ka = (size_t)r0 * 64 + ch0, kb = (size_t)r1 * 64 + ch1;
  size_t vao = (size_t)r0 * 2048 + ch0, vbo = (size_t)r1 * 2048 + ch1;
  short8 sKh0 = *(const short8*)(Khb + ka), sKh1 = *(const short8*)(Khb + kb);
  short8 sKl0 = *(const short8*)(Klb + ka), sKl1 = *(const short8*)(Klb + kb);
  short8 sVh0 = *(const short8*)(Vhb + vao), sVh1 = *(const short8*)(Vhb + vbo);
  short8 sVl0 = *(const short8*)(Vlb + vao), sVl1 = *(const short8*)(Vlb + vbo);

  for (int k0 = 0; k0 < 2048; k0 += 64) {
    __syncthreads();
    *(short8*)(kv0 + dst0) = sKh0;          *(short8*)(kv0 + dst1) = sKh1;
    *(short8*)(kv0 + dst0 + 8192) = sKl0;   *(short8*)(kv0 + dst1 + 8192) = sKl1;
    *(short8*)(kv0 + dst0 + 16384) = sVh0;  *(short8*)(kv0 + dst1 + 16384) = sVh1;
    *(short8*)(kv0 + dst0 + 24576) = sVl0;  *(short8*)(kv0 + dst1 + 24576) = sVl1;
    __syncthreads();
    if (k0 < 2048 - 64) {
      ka += 4096; kb += 4096; vao += 64; vbo += 64;
      sKh0 = *(const short8*)(Khb + ka); sKh1 = *(const short8*)(Khb + kb);
      sKl0 = *(const short8*)(Klb + ka); sKl1 = *(const short8*)(Klb + kb);
      sVh0 = *(const short8*)(Vhb + vao); sVh1 = *(const short8*)(Vhb + vbo);
      sVl0 = *(const short8*)(Vlb + vao); sVl1 = *(const short8*)(Vlb + vbo);
    }

    // ---- S^T = K Q^T : col q = l31, row k = kt*32+(reg&3)+8*(reg>>2)+4*hi ----
    f32x16 s[2] = {};
#pragma unroll
    for (int d = 0; d < 4; ++d) {
#pragma unroll
      for (int kt = 0; kt < 2; ++kt) {
        short8 kfh = *(const short8*)(kv0 + kt * 4096 + va[d]);
        short8 kfl = *(const short8*)(kv0 + 8192 + kt * 4096 + va[d]);
        s[kt] = MFMA32(kfh, qh[d], s[kt]);
        s[kt] = MFMA32(kfh, ql[d], s[kt]);
        s[kt] = MFMA32(kfl, qh[d], s[kt]);
      }
    }

    // ---- mask ----
    const unsigned long long mw = Mb[(size_t)qglob * 32 + (k0 >> 6)];
#pragma unroll
    for (int kt = 0; kt < 2; ++kt)
#pragma unroll
      for (int m = 0; m < 4; ++m) {
        unsigned nib = ((unsigned)(mw >> (kt * 32 + m * 8 + 4 * hi))) & 0xFu;
#pragma unroll
        for (int r = 0; r < 4; ++r)
          s[kt][4 * m + r] = ((nib >> r) & 1u) ? -1e30f : s[kt][4 * m + r];
      }

    // ---- lane-local online softmax (exp2 domain) ----
    float mx = s[0][0];
#pragma unroll
    for (int kt = 0; kt < 2; ++kt)
#pragma unroll
      for (int e = 0; e < 16; ++e) mx = fmaxf(mx, s[kt][e]);
    mx = fmaxf(mx, __shfl_xor(mx, 32));
    const bool grow = __any(mx > mrun + 11.0f);
    const float mnew = grow ? fmaxf(mrun, mx) : mrun;

    float rs = 0.0f;
#pragma unroll
    for (int kt = 0; kt < 2; ++kt)
#pragma unroll
      for (int e = 0; e < 16; ++e) {
        float p = EXP2(s[kt][e] - mnew);
        s[kt][e] = p;
        rs += p;
      }
    rs += __shfl_xor(rs, 32);
    if (grow) {
      float sc = EXP2(mrun - mnew);
      lrun = lrun * sc + rs;
      mrun = mnew;
#pragma unroll
      for (int dt = 0; dt < 2; ++dt)
#pragma unroll
        for (int e = 0; e < 16; ++e) o[dt][e] *= sc;
    } else {
      lrun += rs;
    }

    // ---- P -> PV B-frags in-register ----
    // B-frag(ks = kt*2+sI) dwords: dw0/dw1 (j=0..3) sourced from h=0 lanes,
    // dw2/dw3 (j=4..7) from h=1 lanes, at m = 2*sI + hi_dst.
    short8 fragh[4], fragl[4];
#pragma unroll
    for (int kt = 0; kt < 2; ++kt) {
      unsigned c0h[4], c1h[4], c0l[4], c1l[4];
#pragma unroll
      for (int m = 0; m < 4; ++m) {
        float p0 = s[kt][4 * m + 0], p1 = s[kt][4 * m + 1];
        float p2 = s[kt][4 * m + 2], p3 = s[kt][4 * m + 3];
        unsigned ch0 = cvtpk_bf16(p0, p1);
        unsigned ch1 = cvtpk_bf16(p2, p3);
        float l0 = p0 - __uint_as_float(ch0 << 16);
        float l1 = p1 - __uint_as_float(ch0 & 0xffff0000u);
        float l2 = p2 - __uint_as_float(ch1 << 16);
        float l3 = p3 - __uint_as_float(ch1 & 0xffff0000u);
        c0h[m] = ch0; c1h[m] = ch1;
        c0l[m] = cvtpk_bf16(l0, l1);
        c1l[m] = cvtpk_bf16(l2, l3);
      }
#pragma unroll
      for (int sI = 0; sI < 2; ++sI) {
        const int ks = kt * 2 + sI;
        unsigned dw0, dw1, dw2, dw3;
        xsw<S2>(c0h[2 * sI], c0h[2 * sI + 1], dw0, dw2);
        xsw<S2>(c1h[2 * sI], c1h[2 * sI + 1], dw1, dw3);
        union U { uint4 u; short8 s8; } FH, FL;
        FH.u = make_uint4(dw0, dw1, dw2, dw3);
        xsw<S2>(c0l[2 * sI], c0l[2 * sI + 1], dw0, dw2);
        xsw<S2>(c1l[2 * sI], c1l[2 * sI + 1], dw1, dw3);
        FL.u = make_uint4(dw0, dw1, dw2, dw3);
        fragh[ks] = FH.s8;
        fragl[ks] = FL.s8;
      }
    }

    // ---- O += V^T P : D[row=d][col=q] ----
#pragma unroll
    for (int dt = 0; dt < 2; ++dt) {
#pragma unroll
      for (int ks = 0; ks < 4; ++ks) {
        short8 vfh = *(const short8*)(kv0 + 16384 + dt * 4096 + va[ks]);
        short8 vfl = *(const short8*)(kv0 + 24576 + dt * 4096 + va[ks]);
        o[dt] = MFMA32(vfh, fragh[ks], o[dt]);
        o[dt] = MFMA32(vfh, fragl[ks], o[dt]);
        o[dt] = MFMA32(vfl, fragh[ks], o[dt]);
      }
    }
  }

  // ---- epilogue: O[q][d], d = dt*32 + 8*m + 4*hi + r ----
  const float invl = lrun > 0.0f ? 1.0f / lrun : 0.0f;
#pragma unroll
  for (int dt = 0; dt < 2; ++dt)
#pragma unroll
    for (int m = 0; m < 4; ++m) {
      float4 v;
      v.x = o[dt][4 * m + 0] * invl;
      v.y = o[dt][4 * m + 1] * invl;
      v.z = o[dt][4 * m + 2] * invl;
      v.w = o[dt][4 * m + 3] * invl;
      const int d = dt * 32 + m * 8 + 4 * hi;
      *(float4*)&Ob[(size_t)qglob * 512 + d] = v;
    }
}

// ---------------- Kernel 2: flash attention ----------------
__global__ __launch_bounds__(256, 3) void attn_kernel(
    const unsigned short* __restrict__ Qh, const unsigned short* __restrict__ Ql,
    const unsigned short* __restrict__ Kh, const unsigned short* __restrict__ Kl,
    const unsigned short* __restrict__ Vh, const unsigned short* __restrict__ Vl,
    const unsigned long long* __restrict__ Mp, float* __restrict__ out) {
  __shared__ __align__(16) unsigned short kvb[4][64][64];  // 32 KB, shared by both paths

  // one-time probe of v_permlane32_swap_b32 direction (wave-uniform result)
  const int hi = (threadIdx.x & 63) >> 5;
  unsigned ta = 1u + (unsigned)hi;  // lanes<32: 1, >=32: 2
  unsigned tb = 3u + (unsigned)hi;  // lanes<32: 3, >=32: 4
  permswap(ta, tb);
  // S2 (a.row1<->b.row0): ta' = lane<32 ? 1 : 3.  S1 (a.row0<->b.row1): ta' = lane<32 ? 4 : 2.
  const bool s2 = (__builtin_amdgcn_readfirstlane(ta) == 1u);

  if (s2) attn_body<true>(kvb, Qh, Ql, Kh, Kl, Vh, Vl, Mp, out);
  else    attn_body<false>(kvb, Qh, Ql, Kh, Kl, Vh, Vl, Mp, out);
}

extern "C" void kernel_launch(void* const* d_in, const int* in_sizes, int n_in,
                              void* d_out, int out_size, void* d_ws, size_t ws_size,
                              hipStream_t stream) {
  const float* x = (const float*)d_in[0];
  const void* mask = d_in[1];
  const float* Wq = (const float*)d_in[2];
  const float* Wk = (const float*)d_in[3];
  const float* Wv = (const float*)d_in[4];
  float* out = (float*)d_out;

  const size_t PLANE = (size_t)NBH * NSEQ * DH;  // 4,194,304 ushorts
  unsigned short* Qh = (unsigned short*)d_ws;
  unsigned short* Ql = Qh + PLANE;
  unsigned short* Kh = Ql + PLANE;
  unsigned short* Kl = Kh + PLANE;
  unsigned short* Vh = Kl + PLANE;
  unsigned short* Vl = Vh + PLANE;
  unsigned long long* Mp = (unsigned long long*)(Vl + PLANE);  // 2 MB

  pack_mask<<<1024, 256, 0, stream>>>(mask, Mp);
  proj_kernel<<<dim3(128, 8), 256, 0, stream>>>(x, Wq, Wk, Wv, Qh, Ql, Kh, Kl, Vh, Vl);
  attn_kernel<<<512, 256, 0, stream>>>(Qh, Ql, Kh, Kl, Vh, Vl, Mp, out);
}

// Round 9
// 194.697 us; speedup vs baseline: 1.7388x; 1.0940x over previous
//
#include <hip/hip_runtime.h>

// Attention_29231547416680: B=4, N=2048, CH=512, H=8, D=64, fp32 in/out.
// R9 = R8 + double-buffered K/V LDS (one barrier/iter, stage-ahead pipeline)
//      + s_setprio around MFMA clusters. 32x32x16 MFMAs, 32 q-rows/wave,
//      in-register P->B-frag via cvt_pk + permlane32_swap (probed direction).

typedef float f32x4 __attribute__((ext_vector_type(4)));
typedef float f32x16 __attribute__((ext_vector_type(16)));
typedef short short8 __attribute__((ext_vector_type(8)));

#define MFMA16(a, b, c) __builtin_amdgcn_mfma_f32_16x16x32_bf16((a), (b), (c), 0, 0, 0)
#define MFMA32(a, b, c) __builtin_amdgcn_mfma_f32_32x32x16_bf16((a), (b), (c), 0, 0, 0)

#if __has_builtin(__builtin_amdgcn_exp2f)
#define EXP2(x) __builtin_amdgcn_exp2f(x)
#else
#define EXP2(x) exp2f(x)
#endif

#define NBH 32
#define NSEQ 2048
#define DH 64

__device__ __forceinline__ unsigned short f2bf(float f) {
  unsigned int u = __float_as_uint(f);
  u += 0x7fffu + ((u >> 16) & 1u);  // RTNE
  return (unsigned short)(u >> 16);
}
__device__ __forceinline__ float bf2f(unsigned short h) {
  return __uint_as_float(((unsigned int)h) << 16);
}
__device__ __forceinline__ void split_bf16(float f, unsigned short& hi, unsigned short& lo) {
  hi = f2bf(f);
  lo = f2bf(f - bf2f(hi));
}

// pack two f32 -> dword of 2 bf16 (lo16 = bf16(a), hi16 = bf16(b))
__device__ __forceinline__ unsigned cvtpk_bf16(float a, float b) {
  unsigned d;
  asm("v_cvt_pk_bf16_f32 %0, %1, %2" : "=v"(d) : "v"(a), "v"(b));
  return d;
}
__device__ __forceinline__ void permswap(unsigned& a, unsigned& b) {
  asm("v_permlane32_swap_b32 %0, %1" : "+v"(a), "+v"(b));
}

// Build the two cross-half dwords from an (even-m, odd-m) cvtpk pair.
// lo = (ce.row0 | co.row0), hi = (ce.row1 | co.row1). Direction-agnostic via S2.
template <bool S2>
__device__ __forceinline__ void xsw(unsigned ce, unsigned co, unsigned& lo, unsigned& hi) {
  if (S2) { permswap(ce, co); }
  else    { permswap(co, ce); }
  lo = ce;
  hi = co;
}

// ---------------- mask bit-pack (R5 verbatim) ----------------
__global__ __launch_bounds__(256) void pack_mask(const void* __restrict__ mraw,
                                                 unsigned long long* __restrict__ Mp) {
  const int tid = threadIdx.x;
  __shared__ int s_bad;
  if (tid == 0) s_bad = 0;
  __syncthreads();
  const unsigned int* mw32 = (const unsigned int*)mraw;
  {
    unsigned int w0 = mw32[tid], w1 = mw32[256 + tid];
    bool ok = (w0 == 0u || w0 == 1u || w0 == 0x3f800000u) &&
              (w1 == 0u || w1 == 1u || w1 == 0x3f800000u);
    if (!ok) s_bad = 1;
  }
  __syncthreads();
  const size_t e0 = (size_t)blockIdx.x * 16384 + (size_t)tid * 64;
  unsigned long long bits = 0ull;
  if (s_bad == 0) {
    const uint4* p = (const uint4*)mw32 + (e0 >> 2);
#pragma unroll
    for (int j = 0; j < 16; ++j) {
      uint4 v = p[j];
      unsigned nib = (v.x != 0u) | ((v.y != 0u) << 1) | ((v.z != 0u) << 2) | ((v.w != 0u) << 3);
      bits |= (unsigned long long)nib << (j * 4);
    }
  } else {
    const uint4* p = (const uint4*)((const unsigned char*)mraw + e0);
#pragma unroll
    for (int j = 0; j < 4; ++j) {
      uint4 v = p[j];
      unsigned dw[4] = {v.x, v.y, v.z, v.w};
#pragma unroll
      for (int d = 0; d < 4; ++d) {
        unsigned nib = (((dw[d]) & 0xffu) != 0u) | ((((dw[d] >> 8) & 0xffu) != 0u) << 1) |
                       ((((dw[d] >> 16) & 0xffu) != 0u) << 2) | ((((dw[d] >> 24) & 0xffu) != 0u) << 3);
        bits |= (unsigned long long)nib << ((j * 4 + d) * 4);
      }
    }
  }
  Mp[e0 >> 6] = bits;
}

// ---------------- Kernel 1: QKV projection (R5 verbatim) ----------------
__global__ __launch_bounds__(256) void proj_kernel(
    const float* __restrict__ x,
    const float* __restrict__ Wq, const float* __restrict__ Wk, const float* __restrict__ Wv,
    unsigned short* __restrict__ Qh, unsigned short* __restrict__ Ql,
    unsigned short* __restrict__ Kh, unsigned short* __restrict__ Kl,
    unsigned short* __restrict__ Vh, unsigned short* __restrict__ Vl) {
  const int tid = threadIdx.x;
  const int w = tid >> 6, l = tid & 63;
  const int m0 = blockIdx.x * 64;
  const int h = blockIdx.y;
  const int lrow = l & 15, lg = l >> 4;
  const int rw = (w >> 1) * 32, cw = (w & 1) * 32;

  union LDSU {
    struct {
      unsigned short Ah[64][48], Al[64][48];
      unsigned short Bh[3][64][48], Bl[3][64][48];
    } s;
    unsigned short ob[6][64][72];
  };
  __shared__ LDSU u;

  f32x4 acc[3][2][2] = {};
  const int srow = tid >> 2, sc8 = (tid & 3) * 8;

  for (int k0 = 0; k0 < 512; k0 += 32) {
    __syncthreads();
    {
      const float* xs = &x[(size_t)(m0 + srow) * 512 + k0 + sc8];
      float4 a0 = *(const float4*)xs, a1 = *(const float4*)(xs + 4);
      unsigned short h0, l0, h1, l1, h2, l2, h3, l3;
      split_bf16(a0.x, h0, l0); split_bf16(a0.y, h1, l1);
      split_bf16(a0.z, h2, l2); split_bf16(a0.w, h3, l3);
      *(ushort4*)&u.s.Ah[srow][sc8] = make_ushort4(h0, h1, h2, h3);
      *(ushort4*)&u.s.Al[srow][sc8] = make_ushort4(l0, l1, l2, l3);
      split_bf16(a1.x, h0, l0); split_bf16(a1.y, h1, l1);
      split_bf16(a1.z, h2, l2); split_bf16(a1.w, h3, l3);
      *(ushort4*)&u.s.Ah[srow][sc8 + 4] = make_ushort4(h0, h1, h2, h3);
      *(ushort4*)&u.s.Al[srow][sc8 + 4] = make_ushort4(l0, l1, l2, l3);
      const float* Wz[3] = {Wq, Wk, Wv};
#pragma unroll
      for (int z = 0; z < 3; ++z) {
        const float* ws = &Wz[z][(size_t)(h * 64 + srow) * 512 + k0 + sc8];
        float4 b0 = *(const float4*)ws, b1 = *(const float4*)(ws + 4);
        split_bf16(b0.x, h0, l0); split_bf16(b0.y, h1, l1);
        split_bf16(b0.z, h2, l2); split_bf16(b0.w, h3, l3);
        *(ushort4*)&u.s.Bh[z][srow][sc8] = make_ushort4(h0, h1, h2, h3);
        *(ushort4*)&u.s.Bl[z][srow][sc8] = make_ushort4(l0, l1, l2, l3);
        split_bf16(b1.x, h0, l0); split_bf16(b1.y, h1, l1);
        split_bf16(b1.z, h2, l2); split_bf16(b1.w, h3, l3);
        *(ushort4*)&u.s.Bh[z][srow][sc8 + 4] = make_ushort4(h0, h1, h2, h3);
        *(ushort4*)&u.s.Bl[z][srow][sc8 + 4] = make_ushort4(l0, l1, l2, l3);
      }
    }
    __syncthreads();

    short8 ah[2], al[2];
#pragma unroll
    for (int t = 0; t < 2; ++t) {
      ah[t] = *(const short8*)&u.s.Ah[rw + 16 * t + lrow][lg * 8];
      al[t] = *(const short8*)&u.s.Al[rw + 16 * t + lrow][lg * 8];
    }
#pragma unroll
    for (int z = 0; z < 3; ++z) {
      short8 bh[2], bl[2];
#pragma unroll
      for (int t = 0; t < 2; ++t) {
        bh[t] = *(const short8*)&u.s.Bh[z][cw + 16 * t + lrow][lg * 8];
        bl[t] = *(const short8*)&u.s.Bl[z][cw + 16 * t + lrow][lg * 8];
      }
#pragma unroll
      for (int tm = 0; tm < 2; ++tm)
#pragma unroll
        for (int tn = 0; tn < 2; ++tn) {
          acc[z][tm][tn] = MFMA16(ah[tm], bh[tn], acc[z][tm][tn]);
          acc[z][tm][tn] = MFMA16(ah[tm], bl[tn], acc[z][tm][tn]);
          acc[z][tm][tn] = MFMA16(al[tm], bh[tn], acc[z][tm][tn]);
        }
    }
  }

  __syncthreads();
  const float qsc = 1.4426950408889634f * 0.08838834764831845f;  // log2e/sqrt(128)
#pragma unroll
  for (int z = 0; z < 3; ++z)
#pragma unroll
    for (int tm = 0; tm < 2; ++tm)
#pragma unroll
      for (int tn = 0; tn < 2; ++tn) {
        int d = cw + tn * 16 + lrow;
        int nl = rw + tm * 16 + lg * 4;
#pragma unroll
        for (int r = 0; r < 4; ++r) {
          float v = acc[z][tm][tn][r];
          if (z == 0) v *= qsc;
          unsigned short hi, lo;
          split_bf16(v, hi, lo);
          if (z < 2) {
            u.ob[2 * z][nl + r][d] = hi;
            u.ob[2 * z + 1][nl + r][d] = lo;
          } else {
            u.ob[4][d][nl + r] = hi;
            u.ob[5][d][nl + r] = lo;
          }
        }
      }
  __syncthreads();

  const int orow = tid >> 2, oc = (tid & 3) * 16;
  const int b = m0 >> 11, n0 = m0 & 2047, bhid = b * 8 + h;
  {
    unsigned short* QK[4] = {Qh, Ql, Kh, Kl};
#pragma unroll
    for (int p = 0; p < 4; ++p) {
      size_t base = ((size_t)bhid * 2048 + n0 + orow) * 64 + oc;
      *(short8*)&QK[p][base] = *(const short8*)&u.ob[p][orow][oc];
      *(short8*)&QK[p][base + 8] = *(const short8*)&u.ob[p][orow][oc + 8];
    }
    unsigned short* VV[2] = {Vh, Vl};
#pragma unroll
    for (int p = 0; p < 2; ++p) {
      size_t vb = ((size_t)bhid * 64 + orow) * 2048 + n0 + oc;
      *(short8*)&VV[p][vb] = *(const short8*)&u.ob[4 + p][orow][oc];
      *(short8*)&VV[p][vb + 8] = *(const short8*)&u.ob[4 + p][orow][oc + 8];
    }
  }
}

// ---------------- attention body (template on permswap direction) ----------------
template <bool S2>
__device__ __forceinline__ void attn_body(
    unsigned short (&kvb)[2][4][64][64],
    const unsigned short* __restrict__ Qh, const unsigned short* __restrict__ Ql,
    const unsigned short* __restrict__ Kh, const unsigned short* __restrict__ Kl,
    const unsigned short* __restrict__ Vh, const unsigned short* __restrict__ Vl,
    const unsigned long long* __restrict__ Mp, float* __restrict__ out) {
  const int tid = threadIdx.x;
  const int w = tid >> 6, l = tid & 63;
  const int wl = blockIdx.x;
  const int rm = (wl & 7) * 64 + (wl >> 3);  // XCD swizzle (512 = 8*64, bijective)
  const int q0 = (rm & 15) * 128;
  const int bh = rm >> 4;
  const int b = bh >> 3, h = bh & 7;
  const int l31 = l & 31, hi = l >> 5;
  const int swz = (l31 & 7) << 4;

  const unsigned short* Qhb = Qh + (size_t)bh * NSEQ * DH;
  const unsigned short* Qlb = Ql + (size_t)bh * NSEQ * DH;
  const unsigned short* Khb = Kh + (size_t)bh * NSEQ * DH;
  const unsigned short* Klb = Kl + (size_t)bh * NSEQ * DH;
  const unsigned short* Vhb = Vh + (size_t)bh * DH * NSEQ;
  const unsigned short* Vlb = Vl + (size_t)bh * DH * NSEQ;
  const unsigned long long* Mb = Mp + (size_t)b * NSEQ * 32;
  float* Ob = out + (size_t)b * NSEQ * 512 + h * 64;

  char* kv0 = (char*)&kvb[0][0][0][0];

  // A-frag read offsets (within a 32KB buffer): row = tile32*32 + l31
  int va[4];
#pragma unroll
  for (int d = 0; d < 4; ++d) va[d] = l31 * 128 + (((d * 32) | (hi * 16)) ^ swz);

  // Q B-frags (persistent)
  const size_t qoff = (size_t)(q0 + w * 32 + l31) * 64 + hi * 8;
  short8 qh[4], ql[4];
#pragma unroll
  for (int d = 0; d < 4; ++d) {
    qh[d] = *(const short8*)(Qhb + qoff + d * 16);
    ql[d] = *(const short8*)(Qlb + qoff + d * 16);
  }

  f32x16 o[2] = {};
  float mrun = -1e30f, lrun = 0.0f;
  const int qglob = q0 + w * 32 + l31;

  // staging: 256 threads x 2 chunks x 4 planes
  const int r0 = tid >> 3, ch0 = (tid & 7) * 8;
  const int r1 = (tid + 256) >> 3, ch1 = ((tid + 256) & 7) * 8;
  const int dst0 = r0 * 128 + ((ch0 * 2) ^ ((r0 & 7) << 4));
  const int dst1 = r1 * 128 + ((ch1 * 2) ^ ((r1 & 7) << 4));
  size_t ka = (size_t)r0 * 64 + ch0, kb = (size_t)r1 * 64 + ch1;
  size_t vao = (size_t)r0 * 2048 + ch0, vbo = (size_t)r1 * 2048 + ch1;

  // ---- prologue: tile 0 -> buf0; issue tile-1 loads ----
  short8 sKh0 = *(const short8*)(Khb + ka), sKh1 = *(const short8*)(Khb + kb);
  short8 sKl0 = *(const short8*)(Klb + ka), sKl1 = *(const short8*)(Klb + kb);
  short8 sVh0 = *(const short8*)(Vhb + vao), sVh1 = *(const short8*)(Vhb + vbo);
  short8 sVl0 = *(const short8*)(Vlb + vao), sVl1 = *(const short8*)(Vlb + vbo);
  {
    char* nb = kv0;  // buffer 0
    *(short8*)(nb + dst0) = sKh0;          *(short8*)(nb + dst1) = sKh1;
    *(short8*)(nb + dst0 + 8192) = sKl0;   *(short8*)(nb + dst1 + 8192) = sKl1;
    *(short8*)(nb + dst0 + 16384) = sVh0;  *(short8*)(nb + dst1 + 16384) = sVh1;
    *(short8*)(nb + dst0 + 24576) = sVl0;  *(short8*)(nb + dst1 + 24576) = sVl1;
  }
  ka += 4096; kb += 4096; vao += 64; vbo += 64;
  sKh0 = *(const short8*)(Khb + ka); sKh1 = *(const short8*)(Khb + kb);
  sKl0 = *(const short8*)(Klb + ka); sKl1 = *(const short8*)(Klb + kb);
  sVh0 = *(const short8*)(Vhb + vao); sVh1 = *(const short8*)(Vhb + vbo);
  sVl0 = *(const short8*)(Vlb + vao); sVl1 = *(const short8*)(Vlb + vbo);
  __syncthreads();

  for (int it = 0; it < 32; ++it) {
    char* cur = kv0 + (size_t)(it & 1) * 32768;
    // ---- stage tile it+1 into the other buffer; issue loads for it+2 ----
    if (it < 31) {
      char* nb = kv0 + (size_t)((it + 1) & 1) * 32768;
      *(short8*)(nb + dst0) = sKh0;          *(short8*)(nb + dst1) = sKh1;
      *(short8*)(nb + dst0 + 8192) = sKl0;   *(short8*)(nb + dst1 + 8192) = sKl1;
      *(short8*)(nb + dst0 + 16384) = sVh0;  *(short8*)(nb + dst1 + 16384) = sVh1;
      *(short8*)(nb + dst0 + 24576) = sVl0;  *(short8*)(nb + dst1 + 24576) = sVl1;
      if (it < 30) {
        ka += 4096; kb += 4096; vao += 64; vbo += 64;
        sKh0 = *(const short8*)(Khb + ka); sKh1 = *(const short8*)(Khb + kb);
        sKl0 = *(const short8*)(Klb + ka); sKl1 = *(const short8*)(Klb + kb);
        sVh0 = *(const short8*)(Vhb + vao); sVh1 = *(const short8*)(Vhb + vbo);
        sVl0 = *(const short8*)(Vlb + vao); sVl1 = *(const short8*)(Vlb + vbo);
      }
    }

    // ---- S^T = K Q^T ----
    f32x16 s[2] = {};
    __builtin_amdgcn_s_setprio(1);
#pragma unroll
    for (int d = 0; d < 4; ++d) {
#pragma unroll
      for (int kt = 0; kt < 2; ++kt) {
        short8 kfh = *(const short8*)(cur + kt * 4096 + va[d]);
        short8 kfl = *(const short8*)(cur + 8192 + kt * 4096 + va[d]);
        s[kt] = MFMA32(kfh, qh[d], s[kt]);
        s[kt] = MFMA32(kfh, ql[d], s[kt]);
        s[kt] = MFMA32(kfl, qh[d], s[kt]);
      }
    }
    __builtin_amdgcn_s_setprio(0);

    // ---- mask ----
    const unsigned long long mw = Mb[(size_t)qglob * 32 + it];
#pragma unroll
    for (int kt = 0; kt < 2; ++kt)
#pragma unroll
      for (int m = 0; m < 4; ++m) {
        unsigned nib = ((unsigned)(mw >> (kt * 32 + m * 8 + 4 * hi))) & 0xFu;
#pragma unroll
        for (int r = 0; r < 4; ++r)
          s[kt][4 * m + r] = ((nib >> r) & 1u) ? -1e30f : s[kt][4 * m + r];
      }

    // ---- lane-local online softmax (exp2 domain) ----
    float mx = s[0][0];
#pragma unroll
    for (int kt = 0; kt < 2; ++kt)
#pragma unroll
      for (int e = 0; e < 16; ++e) mx = fmaxf(mx, s[kt][e]);
    mx = fmaxf(mx, __shfl_xor(mx, 32));
    const bool grow = __any(mx > mrun + 11.0f);
    const float mnew = grow ? fmaxf(mrun, mx) : mrun;

    float rs = 0.0f;
#pragma unroll
    for (int kt = 0; kt < 2; ++kt)
#pragma unroll
      for (int e = 0; e < 16; ++e) {
        float p = EXP2(s[kt][e] - mnew);
        s[kt][e] = p;
        rs += p;
      }
    rs += __shfl_xor(rs, 32);
    if (grow) {
      float sc = EXP2(mrun - mnew);
      lrun = lrun * sc + rs;
      mrun = mnew;
#pragma unroll
      for (int dt = 0; dt < 2; ++dt)
#pragma unroll
        for (int e = 0; e < 16; ++e) o[dt][e] *= sc;
    } else {
      lrun += rs;
    }

    // ---- P -> PV B-frags in-register ----
    short8 fragh[4], fragl[4];
#pragma unroll
    for (int kt = 0; kt < 2; ++kt) {
      unsigned c0h[4], c1h[4], c0l[4], c1l[4];
#pragma unroll
      for (int m = 0; m < 4; ++m) {
        float p0 = s[kt][4 * m + 0], p1 = s[kt][4 * m + 1];
        float p2 = s[kt][4 * m + 2], p3 = s[kt][4 * m + 3];
        unsigned ch0 = cvtpk_bf16(p0, p1);
        unsigned ch1 = cvtpk_bf16(p2, p3);
        float l0 = p0 - __uint_as_float(ch0 << 16);
        float l1 = p1 - __uint_as_float(ch0 & 0xffff0000u);
        float l2 = p2 - __uint_as_float(ch1 << 16);
        float l3 = p3 - __uint_as_float(ch1 & 0xffff0000u);
        c0h[m] = ch0; c1h[m] = ch1;
        c0l[m] = cvtpk_bf16(l0, l1);
        c1l[m] = cvtpk_bf16(l2, l3);
      }
#pragma unroll
      for (int sI = 0; sI < 2; ++sI) {
        const int ks = kt * 2 + sI;
        unsigned dw0, dw1, dw2, dw3;
        xsw<S2>(c0h[2 * sI], c0h[2 * sI + 1], dw0, dw2);
        xsw<S2>(c1h[2 * sI], c1h[2 * sI + 1], dw1, dw3);
        union U { uint4 u; short8 s8; } FH, FL;
        FH.u = make_uint4(dw0, dw1, dw2, dw3);
        xsw<S2>(c0l[2 * sI], c0l[2 * sI + 1], dw0, dw2);
        xsw<S2>(c1l[2 * sI], c1l[2 * sI + 1], dw1, dw3);
        FL.u = make_uint4(dw0, dw1, dw2, dw3);
        fragh[ks] = FH.s8;
        fragl[ks] = FL.s8;
      }
    }

    // ---- O += V^T P ----
    __builtin_amdgcn_s_setprio(1);
#pragma unroll
    for (int dt = 0; dt < 2; ++dt) {
#pragma unroll
      for (int ks = 0; ks < 4; ++ks) {
        short8 vfh = *(const short8*)(cur + 16384 + dt * 4096 + va[ks]);
        short8 vfl = *(const short8*)(cur + 24576 + dt * 4096 + va[ks]);
        o[dt] = MFMA32(vfh, fragh[ks], o[dt]);
        o[dt] = MFMA32(vfh, fragl[ks], o[dt]);
        o[dt] = MFMA32(vfl, fragh[ks], o[dt]);
      }
    }
    __builtin_amdgcn_s_setprio(0);

    __syncthreads();  // buf[(it+1)&1] writes visible; cur free for reuse next iter
  }

  // ---- epilogue: O[q][d], d = dt*32 + 8*m + 4*hi + r ----
  const float invl = lrun > 0.0f ? 1.0f / lrun : 0.0f;
#pragma unroll
  for (int dt = 0; dt < 2; ++dt)
#pragma unroll
    for (int m = 0; m < 4; ++m) {
      float4 v;
      v.x = o[dt][4 * m + 0] * invl;
      v.y = o[dt][4 * m + 1] * invl;
      v.z = o[dt][4 * m + 2] * invl;
      v.w = o[dt][4 * m + 3] * invl;
      const int d = dt * 32 + m * 8 + 4 * hi;
      *(float4*)&Ob[(size_t)qglob * 512 + d] = v;
    }
}

// ---------------- Kernel 2: flash attention ----------------
__global__ __launch_bounds__(256, 2) void attn_kernel(
    const unsigned short* __restrict__ Qh, const unsigned short* __restrict__ Ql,
    const unsigned short* __restrict__ Kh, const unsigned short* __restrict__ Kl,
    const unsigned short* __restrict__ Vh, const unsigned short* __restrict__ Vl,
    const unsigned long long* __restrict__ Mp, float* __restrict__ out) {
  __shared__ __align__(16) unsigned short kvb[2][4][64][64];  // 64 KB double buffer

  // one-time probe of v_permlane32_swap_b32 direction (wave-uniform result)
  const int hi = (threadIdx.x & 63) >> 5;
  unsigned ta = 1u + (unsigned)hi;
  unsigned tb = 3u + (unsigned)hi;
  permswap(ta, tb);
  const bool s2 = (__builtin_amdgcn_readfirstlane(ta) == 1u);

  if (s2) attn_body<true>(kvb, Qh, Ql, Kh, Kl, Vh, Vl, Mp, out);
  else    attn_body<false>(kvb, Qh, Ql, Kh, Kl, Vh, Vl, Mp, out);
}

extern "C" void kernel_launch(void* const* d_in, const int* in_sizes, int n_in,
                              void* d_out, int out_size, void* d_ws, size_t ws_size,
                              hipStream_t stream) {
  const float* x = (const float*)d_in[0];
  const void* mask = d_in[1];
  const float* Wq = (const float*)d_in[2];
  const float* Wk = (const float*)d_in[3];
  const float* Wv = (const float*)d_in[4];
  float* out = (float*)d_out;

  const size_t PLANE = (size_t)NBH * NSEQ * DH;  // 4,194,304 ushorts
  unsigned short* Qh = (unsigned short*)d_ws;
  unsigned short* Ql = Qh + PLANE;
  unsigned short* Kh = Ql + PLANE;
  unsigned short* Kl = Kh + PLANE;
  unsigned short* Vh = Kl + PLANE;
  unsigned short* Vl = Vh + PLANE;
  unsigned long long* Mp = (unsigned long long*)(Vl + PLANE);  // 2 MB

  pack_mask<<<1024, 256, 0, stream>>>(mask, Mp);
  proj_kernel<<<dim3(128, 8), 256, 0, stream>>>(x, Wq, Wk, Wv, Qh, Ql, Kh, Kl, Vh, Vl);
  attn_kernel<<<512, 256, 0, stream>>>(Qh, Ql, Kh, Kl, Vh, Vl, Mp, out);
}